// Round 1
// baseline (534.342 us; speedup 1.0000x reference)
//
#include <hip/hip_runtime.h>

// SkelConv: masked conv1d, x(32,103,8192) f32, w(206,103,15) f32, mask makes
// per-out-joint input-channel sets CONTIGUOUS ranges. Compute-bound on fp32
// vector ALU (9.63e9 sparse MACs -> ~122us floor at 157.3 TF).

#define C_INCH 103
#define C_OUTCH 206
#define T_LEN 8192
#define B_N 32
#define KW 15
#define PADW 7
#define NJT 25

#define T_TILE 512
#define XS_STRIDE 528
#define XS_COLS 526   // T_TILE + KW - 1
#define WC_TOTAL 39552

// Per-joint geometry (hard-coded from CONV_MAP; mask is still multiplied in
// during prep so correctness only requires this to be a superset).
__device__ __forceinline__ void joint_params(int jt, int& o0, int& ow, int& ci0,
                                             int& iw, int& ow_pad, int& wbase) {
  if (jt == 0)        { o0 = 0;             ow = 14; ci0 = 0;        iw = 11; ow_pad = 16; wbase = 0; }
  else if (jt == 1)   { o0 = 14;            ow = 8;  ci0 = 0;        iw = 15; ow_pad = 8;  wbase = 2816; }
  else if (jt <= 23)  { o0 = 14+(jt-1)*8;   ow = 8;  ci0 = 4*jt-1;   iw = 12; ow_pad = 8;  wbase = 4736+(jt-2)*1536; }
  else                { o0 = 198;           ow = 8;  ci0 = 95;       iw = 8;  ow_pad = 8;  wbase = 38528; }
}

// Compact masked weights into ws: layout [jt]{ [ci][co_pad][16] }, zero-padded
// in co (co>=ow) and k (k==15) so the main loop is branch-free.
__global__ void prep_weights(const float* __restrict__ w,
                             const float* __restrict__ mask,
                             float* __restrict__ wc) {
  int jt = blockIdx.x;
  int o0, ow, ci0, iw, ow_pad, wbase;
  joint_params(jt, o0, ow, ci0, iw, ow_pad, wbase);
  int n = iw * ow_pad * 16;
  for (int i = threadIdx.x; i < n; i += blockDim.x) {
    int k  = i & 15;
    int r  = i >> 4;
    int co = r & (ow_pad - 1);
    int ci = r / ow_pad;          // ow_pad is 8 or 16 -> shift
    float v = 0.f;
    if (k < KW && co < ow) {
      int gi = ((o0 + co) * C_INCH + (ci0 + ci)) * KW + k;
      v = w[gi] * mask[gi];
    }
    wc[wbase + i] = v;
  }
}

__global__ __launch_bounds__(256, 4) void skelconv_main(
    const float* __restrict__ x, const float* __restrict__ wc,
    const float* __restrict__ biases, float* __restrict__ out) {
  int bid = blockIdx.x;
  int jt  = bid % NJT;          // joint fastest -> adjacent blocks share x rows (L2)
  int rem = bid / NJT;
  int tt  = rem & 15;           // 8192/512 = 16 t-tiles
  int b   = rem >> 4;
  int t0  = tt * T_TILE;

  int o0, ow, ci0, iw, ow_pad, wbase;
  joint_params(jt, o0, ow, ci0, iw, ow_pad, wbase);

  __shared__ float xs[15 * XS_STRIDE];

  // Stage x window [t0-7, t0+519) for this joint's iw input rows.
  for (int ci = 0; ci < iw; ++ci) {
    const float* xrow = x + ((size_t)b * C_INCH + (ci0 + ci)) * T_LEN;
    for (int c = threadIdx.x; c < XS_COLS; c += 256) {
      int gt = t0 - PADW + c;
      float v = (gt >= 0 && gt < T_LEN) ? xrow[gt] : 0.f;
      xs[ci * XS_STRIDE + c] = v;
    }
  }
  __syncthreads();

  int wid  = threadIdx.x >> 6;
  int lane = threadIdx.x & 63;
  int n_cosets = ow_pad >> 2;   // 2 (most joints) or 4 (root)
  int npairs   = n_cosets * 2;  // (coset, t-half) work items

  for (int pair = wid; pair < npairs; pair += 4) {
    int coset   = pair >> 1;
    int thalf   = pair & 1;
    int co_base = coset * 4;

    float acc[4][4];
    #pragma unroll
    for (int a = 0; a < 4; ++a)
      #pragma unroll
      for (int c = 0; c < 4; ++c) acc[a][c] = 0.f;

    int tb = thalf * 256 + lane;
    for (int ci = 0; ci < iw; ++ci) {
      // Wave-uniform weight base -> s_load broadcast (SGPR operand of v_fma).
      int uoff = __builtin_amdgcn_readfirstlane(wbase + (ci * ow_pad + co_base) * 16);
      const float4* wp = (const float4*)(wc + uoff);
      float wr[4][16];
      #pragma unroll
      for (int c2 = 0; c2 < 4; ++c2)
        #pragma unroll
        for (int q = 0; q < 4; ++q) {
          float4 f = wp[c2 * 4 + q];
          wr[c2][q*4+0] = f.x; wr[c2][q*4+1] = f.y;
          wr[c2][q*4+2] = f.z; wr[c2][q*4+3] = f.w;
        }

      const float* xrow = xs + ci * XS_STRIDE + tb;
      #pragma unroll
      for (int k = 0; k < KW; ++k) {
        #pragma unroll
        for (int ch = 0; ch < 4; ++ch) {
          float xv = xrow[ch * 64 + k];   // ds_read_b32, imm offset, stride-1 lanes
          #pragma unroll
          for (int c2 = 0; c2 < 4; ++c2)
            acc[c2][ch] = fmaf(wr[c2][k], xv, acc[c2][ch]);
        }
      }
    }

    #pragma unroll
    for (int c2 = 0; c2 < 4; ++c2) {
      int co = co_base + c2;
      if (co < ow) {                      // padded co lanes computed zeros; skip store
        int gco = o0 + co;
        float bv = biases[gco];
        float* orow = out + ((size_t)b * C_OUTCH + gco) * T_LEN + t0 + thalf * 256 + lane;
        #pragma unroll
        for (int ch = 0; ch < 4; ++ch)
          orow[ch * 64] = acc[c2][ch] + bv;
      }
    }
  }
}

extern "C" void kernel_launch(void* const* d_in, const int* in_sizes, int n_in,
                              void* d_out, int out_size, void* d_ws, size_t ws_size,
                              hipStream_t stream) {
  const float* x      = (const float*)d_in[0];
  const float* w      = (const float*)d_in[1];
  const float* biases = (const float*)d_in[2];
  const float* mask   = (const float*)d_in[3];
  float* out = (float*)d_out;
  float* wc  = (float*)d_ws;   // 39552 floats = 158 KB

  hipLaunchKernelGGL(prep_weights, dim3(NJT), dim3(256), 0, stream, w, mask, wc);
  int nblocks = NJT * B_N * (T_LEN / T_TILE);   // 12800
  hipLaunchKernelGGL(skelconv_main, dim3(nblocks), dim3(256), 0, stream, x, wc, biases, out);
}

// Round 2
// 525.051 us; speedup vs baseline: 1.0177x; 1.0177x over previous
//
#include <hip/hip_runtime.h>

// SkelConv: masked conv1d, x(32,103,8192) f32, w(206,103,15) f32.
// Per-out-joint input-channel sets are CONTIGUOUS ranges -> dense micro-conv
// per joint. fp32 vector-ALU compute floor ~124us (19.4 GFLOP @ 157.3 TF).
// R2: lane owns 4 consecutive t; window via 5x ds_read_b128 per ci
// (was 60x ds_read_b32 -> LDS-pipe-bound at 128 B/cyc/CU).

#define C_INCH 103
#define C_OUTCH 206
#define T_LEN 8192
#define B_N 32
#define KW 15
#define PADW 7
#define NJT 25

#define T_TILE 512
#define XS_STRIDE 528          // floats; 2112 B -> rows stay 16B-aligned
#define XS_COLS 526            // T_TILE + KW - 1

__device__ __forceinline__ void joint_params(int jt, int& o0, int& ow, int& ci0,
                                             int& iw, int& ow_pad, int& wbase) {
  if (jt == 0)        { o0 = 0;             ow = 14; ci0 = 0;        iw = 11; ow_pad = 16; wbase = 0; }
  else if (jt == 1)   { o0 = 14;            ow = 8;  ci0 = 0;        iw = 15; ow_pad = 8;  wbase = 2816; }
  else if (jt <= 23)  { o0 = 14+(jt-1)*8;   ow = 8;  ci0 = 4*jt-1;   iw = 12; ow_pad = 8;  wbase = 4736+(jt-2)*1536; }
  else                { o0 = 198;           ow = 8;  ci0 = 95;       iw = 8;  ow_pad = 8;  wbase = 38528; }
}

// Compact masked weights: layout [jt]{ [ci][co_pad][16] }, zero-padded in co
// and k so the main loop is branch-free.
__global__ void prep_weights(const float* __restrict__ w,
                             const float* __restrict__ mask,
                             float* __restrict__ wc) {
  int jt = blockIdx.x;
  int o0, ow, ci0, iw, ow_pad, wbase;
  joint_params(jt, o0, ow, ci0, iw, ow_pad, wbase);
  int n = iw * ow_pad * 16;
  for (int i = threadIdx.x; i < n; i += blockDim.x) {
    int k  = i & 15;
    int r  = i >> 4;
    int co = r & (ow_pad - 1);
    int ci = r / ow_pad;
    float v = 0.f;
    if (k < KW && co < ow) {
      int gi = ((o0 + co) * C_INCH + (ci0 + ci)) * KW + k;
      v = w[gi] * mask[gi];
    }
    wc[wbase + i] = v;
  }
}

__global__ __launch_bounds__(256, 5) void skelconv_main(
    const float* __restrict__ x, const float* __restrict__ wc,
    const float* __restrict__ biases, float* __restrict__ out) {
  int bid = blockIdx.x;
  int jt  = bid % NJT;          // joint fastest -> adjacent blocks share x rows (L2)
  int rem = bid / NJT;
  int tt  = rem & 15;           // 8192/512 = 16 t-tiles
  int b   = rem >> 4;
  int t0  = tt * T_TILE;

  int o0, ow, ci0, iw, ow_pad, wbase;
  joint_params(jt, o0, ow, ci0, iw, ow_pad, wbase);

  __shared__ float xs[15 * XS_STRIDE];

  // Stage x window [t0-7, t0+519) for this joint's iw input rows.
  for (int ci = 0; ci < iw; ++ci) {
    const float* xrow = x + ((size_t)b * C_INCH + (ci0 + ci)) * T_LEN;
    for (int c = threadIdx.x; c < XS_COLS; c += 256) {
      int gt = t0 - PADW + c;
      float v = (gt >= 0 && gt < T_LEN) ? xrow[gt] : 0.f;
      xs[ci * XS_STRIDE + c] = v;
    }
  }
  __syncthreads();

  int wid  = threadIdx.x >> 6;
  int lane = threadIdx.x & 63;
  int n_cosets = ow_pad >> 2;   // 2 (most joints) or 4 (root)
  int npairs   = n_cosets * 2;  // (coset, t-half) work items

  for (int pair = wid; pair < npairs; pair += 4) {
    int coset   = pair >> 1;
    int thalf   = pair & 1;
    int co_base = coset * 4;
    int j0      = thalf * 256 + 4 * lane;   // lane's first output col in tile

    float acc[4][4];                        // [c2][ts]
    #pragma unroll
    for (int a = 0; a < 4; ++a)
      #pragma unroll
      for (int c = 0; c < 4; ++c) acc[a][c] = 0.f;

    for (int ci = 0; ci < iw; ++ci) {
      // Wave-uniform weight base -> scalar loads, SGPR operand of v_fma.
      int uoff = __builtin_amdgcn_readfirstlane(wbase + (ci * ow_pad + co_base) * 16);
      const float* wp = wc + uoff;
      float wv[4][KW];
      #pragma unroll
      for (int c2 = 0; c2 < 4; ++c2)
        #pragma unroll
        for (int k = 0; k < KW; ++k)
          wv[c2][k] = wp[c2 * 16 + k];

      // Lane's 20-float sliding window: 5x ds_read_b128, 16B-aligned.
      const float4* xv = (const float4*)(xs + ci * XS_STRIDE + j0);
      float X[20];
      #pragma unroll
      for (int q = 0; q < 5; ++q) {
        float4 f = xv[q];
        X[4*q+0] = f.x; X[4*q+1] = f.y; X[4*q+2] = f.z; X[4*q+3] = f.w;
      }

      #pragma unroll
      for (int c2 = 0; c2 < 4; ++c2)
        #pragma unroll
        for (int k = 0; k < KW; ++k)
          #pragma unroll
          for (int ts = 0; ts < 4; ++ts)
            acc[c2][ts] = fmaf(wv[c2][k], X[k + ts], acc[c2][ts]);
    }

    #pragma unroll
    for (int c2 = 0; c2 < 4; ++c2) {
      int co = co_base + c2;
      if (co < ow) {                        // padded co lanes computed zeros; skip store
        int gco = o0 + co;
        float bv = biases[gco];
        float4 o;
        o.x = acc[c2][0] + bv; o.y = acc[c2][1] + bv;
        o.z = acc[c2][2] + bv; o.w = acc[c2][3] + bv;
        float* orow = out + ((size_t)b * C_OUTCH + gco) * T_LEN + t0 + j0;
        *(float4*)orow = o;                 // coalesced 16B/lane store
      }
    }
  }
}

extern "C" void kernel_launch(void* const* d_in, const int* in_sizes, int n_in,
                              void* d_out, int out_size, void* d_ws, size_t ws_size,
                              hipStream_t stream) {
  const float* x      = (const float*)d_in[0];
  const float* w      = (const float*)d_in[1];
  const float* biases = (const float*)d_in[2];
  const float* mask   = (const float*)d_in[3];
  float* out = (float*)d_out;
  float* wc  = (float*)d_ws;   // 39552 floats = 158 KB

  hipLaunchKernelGGL(prep_weights, dim3(NJT), dim3(256), 0, stream, w, mask, wc);
  int nblocks = NJT * B_N * (T_LEN / T_TILE);   // 12800
  hipLaunchKernelGGL(skelconv_main, dim3(nblocks), dim3(256), 0, stream, x, wc, biases, out);
}

// Round 3
// 341.797 us; speedup vs baseline: 1.5633x; 1.5361x over previous
//
#include <hip/hip_runtime.h>

// SkelConv via bf16 MFMA implicit-GEMM.
// Joints grouped into 14 M=16 tiles: [jt0], [jt1], 11 pairs (2j,2j+1) whose
// ci-union is exactly 16 contiguous rows, [jt24]. K = 16 ci x 16 taps = 256
// (8 steps of mfma_f32_16x16x32_bf16). K ordered kk*16+ci so a lane's B
// fragment (8 consecutive k) = 8 consecutive ci at one column -> x staged
// TRANSPOSED in LDS as bf16 with 48 B column stride (16B-aligned b128 reads).
// fp32 accumulate in MFMA. Predicted memory-bound ~80 us (453 MB HBM).

typedef __attribute__((ext_vector_type(8))) short s16x8;
typedef __attribute__((ext_vector_type(4))) float f32x4;

#define T_LEN 8192
#define B_N 32
#define C_INCH 103
#define C_OUTCH 206
#define NTILE 14
#define TTILE 512
#define NCOLS 528            // TTILE + 16 halo (taps reach -7..+8)
#define LDS_STRIDE 48        // bytes per staged column (16 ci * 2B, padded)
#define KSTEPS 8             // K = 256

// bf16 round-to-nearest-even, returns raw bits
__device__ __forceinline__ unsigned short f2bf(float f) {
  union { float f; unsigned u; } v; v.f = f;
  unsigned r = v.u + 0x7FFFu + ((v.u >> 16) & 1u);
  return (unsigned short)(r >> 16);
}

__device__ __forceinline__ void tile_params(int t, int& co_b, int& nr, int& ci_b) {
  if (t == 0)       { co_b = 0;   nr = 14; ci_b = 0;  }      // jt0: ci 0..10 used
  else if (t == 1)  { co_b = 14;  nr = 8;  ci_b = 0;  }      // jt1: ci 0..14 used
  else if (t <= 12) { int j = t - 1;                          // pair (2j, 2j+1)
                      co_b = 14 + (2*j - 1) * 8; nr = 16; ci_b = 8*j - 1; }
  else              { co_b = 198; nr = 8;  ci_b = 87; }      // jt24: ci 95..102 used
}

// Pack masked weights in exact MFMA A-fragment layout, bf16:
// wA[((tile*8 + s)*64 + lane)*8 + j] = A[m=lane&15][k=32s + (lane>>4)*8 + j]
// with k -> (kk = k>>4, ci_l = k&15); zeros for kk==15, invalid rows, masked.
__global__ void prep_weights(const float* __restrict__ w,
                             const float* __restrict__ mask,
                             unsigned short* __restrict__ wA) {
  int tile = blockIdx.x >> 3;
  int s    = blockIdx.x & 7;
  int l    = threadIdx.x;            // 0..63
  int co_b, nr, ci_b; tile_params(tile, co_b, nr, ci_b);
  int m  = l & 15;
  int q  = l >> 4;
  int kk = 2 * s + (q >> 1);
  int ci0 = (q & 1) * 8;
  unsigned short* dst = wA + ((size_t)((tile * 8 + s) * 64 + l)) * 8;
  for (int j = 0; j < 8; ++j) {
    int ci = ci_b + ci0 + j;         // always <= 102 by tile construction
    float v = 0.f;
    if (m < nr && kk < 15) {
      int gi = ((co_b + m) * C_INCH + ci) * 15 + kk;
      v = w[gi] * mask[gi];
    }
    dst[j] = f2bf(v);
  }
}

__global__ __launch_bounds__(256, 4) void skelconv_mfma(
    const float* __restrict__ x, const unsigned short* __restrict__ wA,
    const float* __restrict__ biases, float* __restrict__ out) {
  int bid  = blockIdx.x;
  int tile = bid % NTILE;            // tile fastest -> L2 reuse of shared x rows
  int rem  = bid / NTILE;
  int tt   = rem & 15;               // 8192/512 tiles
  int b    = rem >> 4;
  int t0   = tt * TTILE;
  int co_b, nr, ci_b; tile_params(tile, co_b, nr, ci_b);

  __shared__ unsigned short xs[NCOLS * LDS_STRIDE / 2];   // 25344 B

  // Stage x transposed: column c (global t = t0-7+c), 16 ci rows as bf16.
  // Two ci packed per b32 write; global reads coalesced along t.
  for (int i = threadIdx.x; i < 8 * NCOLS; i += 256) {
    int p = i / NCOLS;               // ci pair 0..7
    int c = i - p * NCOLS;
    int ci_l = 2 * p;
    int gt = t0 - 7 + c;
    float v0 = 0.f, v1 = 0.f;
    if (gt >= 0 && gt < T_LEN) {
      const float* xp = x + ((size_t)b * C_INCH + ci_b + ci_l) * T_LEN + gt;
      v0 = xp[0];
      v1 = xp[T_LEN];
    }
    unsigned pk = (unsigned)f2bf(v0) | ((unsigned)f2bf(v1) << 16);
    *(unsigned*)((char*)xs + c * LDS_STRIDE + ci_l * 2) = pk;
  }
  __syncthreads();

  int lane = threadIdx.x & 63;
  int wq   = threadIdx.x >> 6;       // wave's t-quarter (128 t each)
  int q    = lane >> 4;
  int n    = lane & 15;
  int e    = q & 1;                  // ci octet
  int h    = q >> 1;                 // kk low bit

  // A fragments: one dwordx4 per lane per K-step, loaded once (L2-resident).
  s16x8 afr[KSTEPS];
  const s16x8* ap = ((const s16x8*)wA) + (size_t)tile * (KSTEPS * 64);
  #pragma unroll
  for (int s = 0; s < KSTEPS; ++s) afr[s] = ap[s * 64 + lane];

  float bvals[4];
  #pragma unroll
  for (int r = 0; r < 4; ++r) {
    int row = q * 4 + r;
    bvals[r] = (row < nr) ? biases[co_b + row] : 0.f;
  }

  // Each wave: 8 tiles of 16 t; per 16-t tile: 8 (b128 + MFMA) K-steps.
  for (int tau = 0; tau < 8; ++tau) {
    int tb = wq * 128 + tau * 16;    // block-local t of column n's base
    // staged col index cs = tb + n + kk = tb + n + 2s + h
    const char* bbase = (const char*)xs + (tb + n + h) * LDS_STRIDE + e * 16;
    f32x4 acc = {0.f, 0.f, 0.f, 0.f};
    #pragma unroll
    for (int s = 0; s < KSTEPS; ++s) {
      s16x8 bfr = *(const s16x8*)(bbase + s * (2 * LDS_STRIDE));
      acc = __builtin_amdgcn_mfma_f32_16x16x32_bf16(afr[s], bfr, acc, 0, 0, 0);
    }
    int tcol = t0 + tb + n;
    #pragma unroll
    for (int r = 0; r < 4; ++r) {
      int row = q * 4 + r;           // C layout: col = lane&15, row = q*4+r
      if (row < nr)
        out[((size_t)b * C_OUTCH + co_b + row) * T_LEN + tcol] = acc[r] + bvals[r];
    }
  }
}

extern "C" void kernel_launch(void* const* d_in, const int* in_sizes, int n_in,
                              void* d_out, int out_size, void* d_ws, size_t ws_size,
                              hipStream_t stream) {
  const float* x      = (const float*)d_in[0];
  const float* w      = (const float*)d_in[1];
  const float* biases = (const float*)d_in[2];
  const float* mask   = (const float*)d_in[3];
  float* out = (float*)d_out;
  unsigned short* wA = (unsigned short*)d_ws;   // 14*8*64*8*2 = 114688 B

  hipLaunchKernelGGL(prep_weights, dim3(NTILE * KSTEPS), dim3(64), 0, stream,
                     w, mask, wA);
  int nblocks = NTILE * B_N * (T_LEN / TTILE);  // 14*32*16 = 7168
  hipLaunchKernelGGL(skelconv_mfma, dim3(nblocks), dim3(256), 0, stream,
                     x, wA, biases, out);
}